// Round 8
// baseline (370.895 us; speedup 1.0000x reference)
//
#include <hip/hip_runtime.h>
#include <hip/hip_bf16.h>

typedef __attribute__((ext_vector_type(8))) short short8;
typedef __attribute__((ext_vector_type(4))) short short4v;
typedef __attribute__((ext_vector_type(4))) float f32x4;
typedef __bf16 bf16x8 __attribute__((ext_vector_type(8)));
typedef __attribute__((ext_vector_type(2))) unsigned int u32x2;
typedef __attribute__((ext_vector_type(4))) unsigned int u32x4;

#define DEVI static __device__ __forceinline__

DEVI short f2bs(float f) {
    union { __hip_bfloat16 h; short s; } u;
    u.h = __float2bfloat16(f);
    return u.s;
}

// pack two bf16-converted floats into one dword (compiler fuses to v_cvt_pk_bf16_f32)
DEVI unsigned pack2(float a, float b) {
    union { short s[2]; unsigned u; } u;
    u.s[0] = f2bs(a);
    u.s[1] = f2bs(b);
    return u.u;
}

// cross-quad exchange: x,y in; after: x = {x.q0, y.q0, x.q2, y.q2}, y = {x.q1, y.q1, x.q3, y.q3}
DEVI void xchg(unsigned& x, unsigned& y) {
#if __has_builtin(__builtin_amdgcn_permlane32_swap) && __has_builtin(__builtin_amdgcn_permlane16_swap)
    u32x2 t = __builtin_amdgcn_permlane32_swap(x, y, false, false);
    u32x2 r = __builtin_amdgcn_permlane16_swap(t[0], t[1], false, false);
    x = r[0];
    y = r[1];
#else
    asm("v_permlane32_swap_b32 %0, %1" : "+v"(x), "+v"(y));
    asm("v_permlane16_swap_b32 %0, %1" : "+v"(x), "+v"(y));
#endif
}

DEVI f32x4 mfma16(short8 a, short8 b, f32x4 c) {
    return __builtin_amdgcn_mfma_f32_16x16x32_bf16(
        __builtin_bit_cast(bf16x8, a), __builtin_bit_cast(bf16x8, b), c, 0, 0, 0);
}

// async global->LDS, 16B per lane; LDS dest = wave-uniform base + lane*16
DEVI void glds16(const short* g, short* l) {
    __builtin_amdgcn_global_load_lds((const __attribute__((address_space(1))) void*)g,
                                     (__attribute__((address_space(3))) void*)l, 16, 0, 0);
}

// Weight-only fp32->bf16 convert (activations are converted in-flight by qkv_gemm).
__global__ __launch_bounds__(256) void cvt_w(const float4* __restrict__ wq,
                                             const float4* __restrict__ wk,
                                             const float4* __restrict__ wv,
                                             const float4* __restrict__ wo,
                                             short4v* __restrict__ dwq,
                                             short4v* __restrict__ dwk,
                                             short4v* __restrict__ dwv,
                                             short4v* __restrict__ dwo) {
    int i = blockIdx.x * 256 + threadIdx.x;  // n4 = 262144 per tensor
    float4 x;
    short4v s;
    x = wq[i]; s.x = f2bs(x.x); s.y = f2bs(x.y); s.z = f2bs(x.z); s.w = f2bs(x.w); dwq[i] = s;
    x = wk[i]; s.x = f2bs(x.x); s.y = f2bs(x.y); s.z = f2bs(x.z); s.w = f2bs(x.w); dwk[i] = s;
    x = wv[i]; s.x = f2bs(x.x); s.y = f2bs(x.y); s.z = f2bs(x.z); s.w = f2bs(x.w); dwv[i] = s;
    x = wo[i]; s.x = f2bs(x.x); s.y = f2bs(x.y); s.z = f2bs(x.z); s.w = f2bs(x.w); dwo[i] = s;
}

// Shared GEMM body (bf16 A), tile 128x128, K=1024, BK=32, depth-2 issue-early
// pipeline: stage(kt+1) issued BEFORE compute(kt), one barrier per tile.
// Row-pair packing: 16-B chunk i holds row r=2L+(cc&1), k-chunk c=cc>>1 where
// L=i>>3, cc=(i&7)^(L&7) -> bank-conflict-free staging and frag reads.
template <typename EpiT>
DEVI void gemm_body(const short* A, const short* Bw, short* smem, int m0, int n0, EpiT epi) {
    const int t = threadIdx.x;
    const int lane = t & 63, w = t >> 6;
    const int col = lane & 15, quad = lane >> 4;
    const int wm = (w & 1) * 64, wn = (w >> 1) * 64;

    const short* pA0;
    const short* pA1;
    const short* pB0;
    const short* pB1;
    {
        int i0 = w * 64 + lane, i1 = (4 + w) * 64 + lane;
        int L0 = i0 >> 3, cc0 = (i0 & 7) ^ (L0 & 7);
        int r0 = 2 * L0 + (cc0 & 1), c0 = cc0 >> 1;
        int L1 = i1 >> 3, cc1 = (i1 & 7) ^ (L1 & 7);
        int r1 = 2 * L1 + (cc1 & 1), c1 = cc1 >> 1;
        pA0 = A + (size_t)(m0 + r0) * 1024 + c0 * 8;
        pA1 = A + (size_t)(m0 + r1) * 1024 + c1 * 8;
        pB0 = Bw + (size_t)(n0 + r0) * 1024 + c0 * 8;
        pB1 = Bw + (size_t)(n0 + r1) * 1024 + c1 * 8;
    }
    const int posa = (2 * quad + (col & 1)) ^ (col >> 1);
    const int base_a = wm * 32 + (col >> 1) * 64 + posa * 8;
    const int base_b = wn * 32 + (col >> 1) * 64 + posa * 8;

    f32x4 acc[4][4];
#pragma unroll
    for (int i = 0; i < 4; ++i)
#pragma unroll
        for (int j = 0; j < 4; ++j) acc[i][j] = (f32x4){0.f, 0.f, 0.f, 0.f};

    glds16(pA0, smem + w * 512);
    glds16(pA1, smem + (4 + w) * 512);
    glds16(pB0, smem + 4096 + w * 512);
    glds16(pB1, smem + 4096 + (4 + w) * 512);
    pA0 += 32; pA1 += 32; pB0 += 32; pB1 += 32;
    __syncthreads();

#pragma unroll 2
    for (int kt = 0; kt < 32; ++kt) {
        const int cur = kt & 1;
        const short* Cb = smem + cur * 8192;
        if (kt < 31) {
            short* Nb = smem + (cur ^ 1) * 8192;
            glds16(pA0, Nb + w * 512);
            glds16(pA1, Nb + (4 + w) * 512);
            glds16(pB0, Nb + 4096 + w * 512);
            glds16(pB1, Nb + 4096 + (4 + w) * 512);
            pA0 += 32; pA1 += 32; pB0 += 32; pB1 += 32;
        }
        short8 a[4], b[4];
#pragma unroll
        for (int i = 0; i < 4; ++i) a[i] = *(const short8*)(Cb + base_a + i * 512);
#pragma unroll
        for (int i = 0; i < 4; ++i) b[i] = *(const short8*)(Cb + 4096 + base_b + i * 512);
        __builtin_amdgcn_s_setprio(1);
#pragma unroll
        for (int mi = 0; mi < 4; ++mi)
#pragma unroll
            for (int ni = 0; ni < 4; ++ni)
                acc[mi][ni] = mfma16(a[mi], b[ni], acc[mi][ni]);
        __builtin_amdgcn_s_setprio(0);
        __syncthreads();
    }
    epi(acc, wm, wn, col, quad);
}

// GEMM body with fp32 A fused conversion (T14 issue-early/write-late):
// per tile, 4 float4 A-loads + 2 glds16 B issue BEFORE compute; after compute,
// cvt_pk packs A to bf16 and 2 ds_write_b128 land it in the same swizzled slots
// glds16 would have used (byte-identical LDS image); __syncthreads drains vm+lgkm.
template <typename EpiT>
DEVI void gemm_body_f32a(const float* A32, const short* Bw, short* smem, int m0, int n0,
                         EpiT epi) {
    const int t = threadIdx.x;
    const int lane = t & 63, w = t >> 6;
    const int col = lane & 15, quad = lane >> 4;
    const int wm = (w & 1) * 64, wn = (w >> 1) * 64;

    const float* pA0;
    const float* pA1;
    const short* pB0;
    const short* pB1;
    int d0, d1;  // LDS chunk slots (shorts) for the two A chunks
    {
        int i0 = w * 64 + lane, i1 = (4 + w) * 64 + lane;
        int L0 = i0 >> 3, cc0 = (i0 & 7) ^ (L0 & 7);
        int r0 = 2 * L0 + (cc0 & 1), c0 = cc0 >> 1;
        int L1 = i1 >> 3, cc1 = (i1 & 7) ^ (L1 & 7);
        int r1 = 2 * L1 + (cc1 & 1), c1 = cc1 >> 1;
        pA0 = A32 + (size_t)(m0 + r0) * 1024 + c0 * 8;
        pA1 = A32 + (size_t)(m0 + r1) * 1024 + c1 * 8;
        pB0 = Bw + (size_t)(n0 + r0) * 1024 + c0 * 8;
        pB1 = Bw + (size_t)(n0 + r1) * 1024 + c1 * 8;
        d0 = i0 * 8;  // == w*512 + lane*8 (matches glds16's lane*16B rule)
        d1 = i1 * 8;
    }
    const int posa = (2 * quad + (col & 1)) ^ (col >> 1);
    const int base_a = wm * 32 + (col >> 1) * 64 + posa * 8;
    const int base_b = wn * 32 + (col >> 1) * 64 + posa * 8;

    f32x4 acc[4][4];
#pragma unroll
    for (int i = 0; i < 4; ++i)
#pragma unroll
        for (int j = 0; j < 4; ++j) acc[i][j] = (f32x4){0.f, 0.f, 0.f, 0.f};

    // prologue: stage tile 0 into buffer 0
    {
        float4 a00 = *(const float4*)pA0, a01 = *(const float4*)(pA0 + 4);
        float4 a10 = *(const float4*)pA1, a11 = *(const float4*)(pA1 + 4);
        glds16(pB0, smem + 4096 + w * 512);
        glds16(pB1, smem + 4096 + (4 + w) * 512);
        pA0 += 32; pA1 += 32; pB0 += 32; pB1 += 32;
        u32x4 s0 = {pack2(a00.x, a00.y), pack2(a00.z, a00.w),
                    pack2(a01.x, a01.y), pack2(a01.z, a01.w)};
        u32x4 s1 = {pack2(a10.x, a10.y), pack2(a10.z, a10.w),
                    pack2(a11.x, a11.y), pack2(a11.z, a11.w)};
        *(u32x4*)(smem + d0) = s0;
        *(u32x4*)(smem + d1) = s1;
    }
    __syncthreads();

#pragma unroll 2
    for (int kt = 0; kt < 32; ++kt) {
        const int cur = kt & 1;
        const short* Cb = smem + cur * 8192;
        short* Nb = smem + (cur ^ 1) * 8192;
        float4 a00, a01, a10, a11;
        if (kt < 31) {  // issue next-tile loads BEFORE compute
            a00 = *(const float4*)pA0; a01 = *(const float4*)(pA0 + 4);
            a10 = *(const float4*)pA1; a11 = *(const float4*)(pA1 + 4);
            glds16(pB0, Nb + 4096 + w * 512);
            glds16(pB1, Nb + 4096 + (4 + w) * 512);
            pA0 += 32; pA1 += 32; pB0 += 32; pB1 += 32;
        }
        short8 a[4], b[4];
#pragma unroll
        for (int i = 0; i < 4; ++i) a[i] = *(const short8*)(Cb + base_a + i * 512);
#pragma unroll
        for (int i = 0; i < 4; ++i) b[i] = *(const short8*)(Cb + 4096 + base_b + i * 512);
        __builtin_amdgcn_s_setprio(1);
#pragma unroll
        for (int mi = 0; mi < 4; ++mi)
#pragma unroll
            for (int ni = 0; ni < 4; ++ni)
                acc[mi][ni] = mfma16(a[mi], b[ni], acc[mi][ni]);
        __builtin_amdgcn_s_setprio(0);
        if (kt < 31) {  // convert + write-late; HBM latency hid under the MFMAs
            u32x4 s0 = {pack2(a00.x, a00.y), pack2(a00.z, a00.w),
                        pack2(a01.x, a01.y), pack2(a01.z, a01.w)};
            u32x4 s1 = {pack2(a10.x, a10.y), pack2(a10.z, a10.w),
                        pack2(a11.x, a11.y), pack2(a11.z, a11.w)};
            *(u32x4*)(Nb + d0) = s0;
            *(u32x4*)(Nb + d1) = s1;
        }
        __syncthreads();
    }
    epi(acc, wm, wn, col, quad);
}

// Fused Q/K/V projection reading fp32 activations directly (in-flight bf16 cvt).
// XCD-aware bijective swizzle: 1536 blocks = 8 XCDs x 192.
__global__ __launch_bounds__(256) void qkv_gemm(const float* __restrict__ xq,
                                                const float* __restrict__ xk,
                                                const float* __restrict__ xv,
                                                const short* __restrict__ wq,
                                                const short* __restrict__ wk,
                                                const short* __restrict__ wv,
                                                short* __restrict__ qp,
                                                short* __restrict__ kp,
                                                short* __restrict__ vpt, float qscale) {
    __shared__ __align__(16) short smem[17408];  // staging 16384 | T 128x136
    const int lin = blockIdx.x + (blockIdx.y << 3) + (blockIdx.z << 9);
    const int wgid = (lin & 7) * 192 + (lin >> 3);
    const int n0 = (wgid & 7) * 128;
    const int m0 = ((wgid >> 3) & 63) * 128;
    const int z = wgid >> 9;
    const float* A = (z == 0) ? xq : (z == 1) ? xk : xv;
    const short* W = (z == 0) ? wq : (z == 1) ? wk : wv;

    if (z < 2) {
        short* outs = (z == 0) ? qp : kp;
        const float scale = (z == 0) ? qscale : 1.0f;
        gemm_body_f32a(A, W, smem, m0, n0,
                       [&](f32x4 (&acc)[4][4], int wm, int wn, int col, int quad) {
            short* T = smem;  // [128 m][136 n-padded]
#pragma unroll
            for (int mi = 0; mi < 4; ++mi)
#pragma unroll
                for (int ni = 0; ni < 4; ++ni)
#pragma unroll
                    for (int r = 0; r < 4; ++r)
                        T[(wm + mi * 16 + quad * 4 + r) * 136 + wn + ni * 16 + col] =
                            f2bs(acc[mi][ni][r] * scale);
            __syncthreads();
            int t = threadIdx.x;
            int ml = t >> 1, nh = (t & 1) * 64;
            int m = m0 + ml;                    // b*2048+s
            int b = m >> 11, s = m & 2047;
#pragma unroll
            for (int j = 0; j < 8; ++j) {
                int n = n0 + nh + j * 8;        // h*64+dk
                short8 vv = *(const short8*)(T + ml * 136 + nh + j * 8);
                size_t off = ((size_t)(b * 16 + (n >> 6)) * 2048 + s) * 64 + (n & 63);
                *(short8*)(outs + off) = vv;
            }
        });
    } else {
        gemm_body_f32a(A, W, smem, m0, n0,
                       [&](f32x4 (&acc)[4][4], int wm, int wn, int col, int quad) {
            short* T = smem;  // [128 n][132 m]
#pragma unroll
            for (int mi = 0; mi < 4; ++mi)
#pragma unroll
                for (int ni = 0; ni < 4; ++ni) {
                    int n_l = wn + ni * 16 + col;
                    int m_l = wm + mi * 16 + quad * 4;
                    short4v sv;
                    sv.x = f2bs(acc[mi][ni][0]); sv.y = f2bs(acc[mi][ni][1]);
                    sv.z = f2bs(acc[mi][ni][2]); sv.w = f2bs(acc[mi][ni][3]);
                    *(short4v*)(T + n_l * 132 + m_l) = sv;
                }
            __syncthreads();
            int t = threadIdx.x;
            int nrow = t >> 1, mh = (t & 1) * 64;
            int b = m0 >> 11, s0 = m0 & 2047;
            size_t base = ((size_t)(b * 1024 + n0 + nrow)) * 2048 + s0 + mh;
#pragma unroll
            for (int j = 0; j < 16; ++j) {
                unsigned long long vv = *(const unsigned long long*)(T + nrow * 132 + mh + j * 4);
                *(unsigned long long*)(vpt + base + j * 4) = vv;
            }
        });
    }
}

__global__ __launch_bounds__(256) void out_gemm(const short* __restrict__ ao,
                                                const short* __restrict__ wo,
                                                float* __restrict__ outf) {
    __shared__ __align__(16) short smem[16896];
    const int lin = blockIdx.x + (blockIdx.y << 3);
    const int wgid = (lin & 7) * 64 + (lin >> 3);
    const int n0 = (wgid & 7) * 128;
    const int m0 = (wgid >> 3) * 128;
    gemm_body(ao, wo, smem, m0, n0, [&](f32x4 (&acc)[4][4], int wm, int wn, int col, int quad) {
#pragma unroll
        for (int mi = 0; mi < 4; ++mi)
#pragma unroll
            for (int ni = 0; ni < 4; ++ni)
#pragma unroll
                for (int r = 0; r < 4; ++r) {
                    int m = m0 + wm + mi * 16 + quad * 4 + r;
                    int n = n0 + wn + ni * 16 + col;
                    outf[(size_t)m * 1024 + n] = acc[mi][ni][r];
                }
    });
}

// Flash attention (round-4 best-measured version): S^T 16x16 MFMA, in-register P
// redistribution (permlane), denominator via ones-MFMA, 2-phase double-buffered
// K/V pipeline. LDS = 32768 B -> 4 blocks/CU. Conflict-free.
__global__ __launch_bounds__(256, 4) void flash_attn(const short* __restrict__ qp,
                                                     const short* __restrict__ kp,
                                                     const short* __restrict__ vpt,
                                                     short* __restrict__ ao) {
    __shared__ __align__(16) short smem[16384];  // Ks2: [2][4096] | Vs2: [2][4096]
    short* Ks2 = smem;
    short* Vs2 = smem + 8192;

    const int t = threadIdx.x, lane = t & 63, w = t >> 6;
    const int col = lane & 15, quad = lane >> 4;
    const int bh = blockIdx.x, q0 = blockIdx.y * 128;
    const short* qb = qp + (size_t)bh * 2048 * 64;
    const short* kb = kp + (size_t)bh * 2048 * 64;
    const short* vb = vpt + (size_t)bh * 64 * 2048;

    // ---- stage Q tile 128x64 (swizzled) into smem[0..8192) ----
#pragma unroll
    for (int j = 0; j < 4; ++j) {
        int cbase = (j * 4 + w) * 64;
        int c = cbase + lane;
        int row = c >> 3, kc = (c & 7) ^ (row & 7);
        glds16(qb + (size_t)(q0 + row) * 64 + kc * 8, smem + cbase * 8);
    }
    __syncthreads();
    short8 bQ[2][2];
#pragma unroll
    for (int qi = 0; qi < 2; ++qi)
#pragma unroll
        for (int ks = 0; ks < 2; ++ks) {
            int row = w * 32 + qi * 16 + col;
            int kc = (ks * 4 + quad) ^ (col & 7);
            bQ[qi][ks] = *(const short8*)(smem + (row * 8 + kc) * 8);
        }
    __syncthreads();

    // hoisted per-lane LDS read bases (shorts)
    const int base2_0 = col * 64 + ((quad ^ (col & 7)) * 8);
    const int base2_1 = col * 64 + (((4 + quad) ^ (col & 7)) * 8);

    // hoisted per-lane global staging pointers (advance per kt)
    const short* kg0;
    const short* kg1;
    const short* vg0;
    const short* vg1;
    {
        int c0 = w * 64 + lane, c1 = (4 + w) * 64 + lane;
        int r0 = c0 >> 3, p0 = c0 & 7, r1 = c1 >> 3, p1 = c1 & 7;
        kg0 = kb + r0 * 64 + ((p0 ^ (r0 & 7)) * 8);
        kg1 = kb + r1 * 64 + ((p1 ^ (r1 & 7)) * 8);
        vg0 = vb + (size_t)r0 * 2048 + ((p0 ^ (r0 & 7)) * 8);
        vg1 = vb + (size_t)r1 * 2048 + ((p1 ^ (r1 & 7)) * 8);
    }

    f32x4 acc_o[2][4], acc_l[2];
#pragma unroll
    for (int qi = 0; qi < 2; ++qi) {
        acc_l[qi] = (f32x4){0.f, 0.f, 0.f, 0.f};
#pragma unroll
        for (int ni = 0; ni < 4; ++ni) acc_o[qi][ni] = (f32x4){0.f, 0.f, 0.f, 0.f};
    }
    const short ONE = 0x3F80;  // bf16 1.0
    const short8 vones = {ONE, ONE, ONE, ONE, ONE, ONE, ONE, ONE};

    // prefetch tile 0 into buffer 0
    glds16(kg0, Ks2 + w * 512);
    glds16(kg1, Ks2 + (4 + w) * 512);
    glds16(vg0, Vs2 + w * 512);
    glds16(vg1, Vs2 + (4 + w) * 512);
    kg0 += 4096; kg1 += 4096; vg0 += 64; vg1 += 64;
    __syncthreads();

#pragma unroll 2
    for (int kt = 0; kt < 32; ++kt) {
        const int cur = kt & 1;
        if (kt < 31) {  // issue next-tile stage BEFORE compute (latency hides under MFMA)
            const int nxt = cur ^ 1;
            glds16(kg0, Ks2 + nxt * 4096 + w * 512);
            glds16(kg1, Ks2 + nxt * 4096 + (4 + w) * 512);
            glds16(vg0, Vs2 + nxt * 4096 + w * 512);
            glds16(vg1, Vs2 + nxt * 4096 + (4 + w) * 512);
            kg0 += 4096; kg1 += 4096; vg0 += 64; vg1 += 64;
        }
        const short* Ks = Ks2 + cur * 4096;
        const short* Vs = Vs2 + cur * 4096;

#pragma unroll
        for (int g = 0; g < 2; ++g) {  // 32-key groups
            unsigned pdw[2][4];
#pragma unroll
            for (int h = 0; h < 2; ++h) {
                const int kei = g * 2 + h;
                f32x4 st0 = (f32x4){0.f, 0.f, 0.f, 0.f};
                f32x4 st1 = (f32x4){0.f, 0.f, 0.f, 0.f};
                __builtin_amdgcn_s_setprio(1);
                {
                    short8 aK0 = *(const short8*)(Ks + base2_0 + kei * 1024);
                    st0 = mfma16(aK0, bQ[0][0], st0);
                    st1 = mfma16(aK0, bQ[1][0], st1);
                    short8 aK1 = *(const short8*)(Ks + base2_1 + kei * 1024);
                    st0 = mfma16(aK1, bQ[0][1], st0);
                    st1 = mfma16(aK1, bQ[1][1], st1);
                }
                __builtin_amdgcn_s_setprio(0);
                {
                    float p0 = __builtin_amdgcn_exp2f(st0[0]);
                    float p1 = __builtin_amdgcn_exp2f(st0[1]);
                    float p2 = __builtin_amdgcn_exp2f(st0[2]);
                    float p3 = __builtin_amdgcn_exp2f(st0[3]);
                    pdw[0][h * 2] = pack2(p0, p1);
                    pdw[0][h * 2 + 1] = pack2(p2, p3);
                }
                {
                    float p0 = __builtin_amdgcn_exp2f(st1[0]);
                    float p1 = __builtin_amdgcn_exp2f(st1[1]);
                    float p2 = __builtin_amdgcn_exp2f(st1[2]);
                    float p3 = __builtin_amdgcn_exp2f(st1[3]);
                    pdw[1][h * 2] = pack2(p0, p1);
                    pdw[1][h * 2 + 1] = pack2(p2, p3);
                }
            }
            // in-register redistribution: quad q ends up with keys g*32 + q*8 .. q*8+7
            xchg(pdw[0][0], pdw[0][2]);
            xchg(pdw[0][1], pdw[0][3]);
            xchg(pdw[1][0], pdw[1][2]);
            xchg(pdw[1][1], pdw[1][3]);
            u32x4 pv0 = {pdw[0][0], pdw[0][1], pdw[0][2], pdw[0][3]};
            u32x4 pv1 = {pdw[1][0], pdw[1][1], pdw[1][2], pdw[1][3]};
            short8 pa0 = __builtin_bit_cast(short8, pv0);
            short8 pa1 = __builtin_bit_cast(short8, pv1);

            const int vb2 = (g == 0) ? base2_0 : base2_1;
            __builtin_amdgcn_s_setprio(1);
#pragma unroll
            for (int ni = 0; ni < 4; ++ni) {
                short8 bv = *(const short8*)(Vs + vb2 + ni * 1024);
                acc_o[0][ni] = mfma16(pa0, bv, acc_o[0][ni]);
                acc_o[1][ni] = mfma16(pa1, bv, acc_o[1][ni]);
            }
            // softmax denominator via ones-MFMA: lands in the epilogue's C layout
            acc_l[0] = mfma16(pa0, vones, acc_l[0]);
            acc_l[1] = mfma16(pa1, vones, acc_l[1]);
            __builtin_amdgcn_s_setprio(0);
        }
        __syncthreads();
    }

    // epilogue: l is already per-lane in C layout (row = quad*4+r), no shuffles
    const int b = bh >> 4, hd = bh & 15;
#pragma unroll
    for (int qi = 0; qi < 2; ++qi)
#pragma unroll
        for (int r = 0; r < 4; ++r) {
            float inv = 1.0f / acc_l[qi][r];
            int q = q0 + w * 32 + qi * 16 + quad * 4 + r;
#pragma unroll
            for (int ni = 0; ni < 4; ++ni)
                ao[((size_t)(b * 2048 + q)) * 1024 + hd * 64 + ni * 16 + col] =
                    f2bs(acc_o[qi][ni][r] * inv);
        }
}

extern "C" void kernel_launch(void* const* d_in, const int* in_sizes, int n_in,
                              void* d_out, int out_size, void* d_ws, size_t ws_size,
                              hipStream_t stream) {
    const float* q  = (const float*)d_in[0];
    const float* k  = (const float*)d_in[1];
    const float* v  = (const float*)d_in[2];
    const float* Wq = (const float*)d_in[3];
    const float* Wk = (const float*)d_in[4];
    const float* Wv = (const float*)d_in[5];
    const float* Wo = (const float*)d_in[6];
    float* out = (float*)d_out;

    short* ws = (short*)d_ws;
    const size_t SZ = (size_t)64 * 2048 * 64;  // 8,388,608
    const size_t WZ = (size_t)1024 * 1024;
    short* ao  = ws;
    short* qp  = ws + SZ;
    short* kp  = ws + 2 * SZ;
    short* wqb = ws + 3 * SZ;
    short* wkb = wqb + WZ;
    short* wvb = wqb + 2 * WZ;
    short* wob = wqb + 3 * WZ;
    // vpt lives in the OUTPUT buffer (16.8 MB needed, 33.5 MB available):
    // qkv writes it, flash reads it, out_gemm overwrites the region with final floats.
    short* vpt = (short*)d_out;

    const float QSCALE = 0.125f * 1.44269504088896f;  // 1/sqrt(64) * log2(e)

    cvt_w<<<dim3(1024), dim3(256), 0, stream>>>(
        (const float4*)Wq, (const float4*)Wk, (const float4*)Wv, (const float4*)Wo,
        (short4v*)wqb, (short4v*)wkb, (short4v*)wvb, (short4v*)wob);
    dim3 blk(256);
    qkv_gemm<<<dim3(8, 64, 3), blk, 0, stream>>>(q, k, v, wqb, wkb, wvb, qp, kp, vpt, QSCALE);
    flash_attn<<<dim3(64, 16), blk, 0, stream>>>(qp, kp, vpt, ao);
    out_gemm<<<dim3(8, 64), blk, 0, stream>>>(ao, wob, out);
}

// Round 9
// 328.251 us; speedup vs baseline: 1.1299x; 1.1299x over previous
//
#include <hip/hip_runtime.h>
#include <hip/hip_bf16.h>

typedef __attribute__((ext_vector_type(8))) short short8;
typedef __attribute__((ext_vector_type(4))) short short4v;
typedef __attribute__((ext_vector_type(4))) float f32x4;
typedef __bf16 bf16x8 __attribute__((ext_vector_type(8)));
typedef __attribute__((ext_vector_type(2))) unsigned int u32x2;
typedef __attribute__((ext_vector_type(4))) unsigned int u32x4;

#define DEVI static __device__ __forceinline__

DEVI short f2bs(float f) {
    union { __hip_bfloat16 h; short s; } u;
    u.h = __float2bfloat16(f);
    return u.s;
}

// pack two bf16-converted floats into one dword (compiler fuses to v_cvt_pk_bf16_f32)
DEVI unsigned pack2(float a, float b) {
    union { short s[2]; unsigned u; } u;
    u.s[0] = f2bs(a);
    u.s[1] = f2bs(b);
    return u.u;
}

// cross-quad exchange: x,y in; after: x = {x.q0, y.q0, x.q2, y.q2}, y = {x.q1, y.q1, x.q3, y.q3}
DEVI void xchg(unsigned& x, unsigned& y) {
#if __has_builtin(__builtin_amdgcn_permlane32_swap) && __has_builtin(__builtin_amdgcn_permlane16_swap)
    u32x2 t = __builtin_amdgcn_permlane32_swap(x, y, false, false);
    u32x2 r = __builtin_amdgcn_permlane16_swap(t[0], t[1], false, false);
    x = r[0];
    y = r[1];
#else
    asm("v_permlane32_swap_b32 %0, %1" : "+v"(x), "+v"(y));
    asm("v_permlane16_swap_b32 %0, %1" : "+v"(x), "+v"(y));
#endif
}

DEVI f32x4 mfma16(short8 a, short8 b, f32x4 c) {
    return __builtin_amdgcn_mfma_f32_16x16x32_bf16(
        __builtin_bit_cast(bf16x8, a), __builtin_bit_cast(bf16x8, b), c, 0, 0, 0);
}

// async global->LDS, 16B per lane; LDS dest = wave-uniform base + lane*16
DEVI void glds16(const short* g, short* l) {
    __builtin_amdgcn_global_load_lds((const __attribute__((address_space(1))) void*)g,
                                     (__attribute__((address_space(3))) void*)l, 16, 0, 0);
}

// Merged fp32->bf16 convert: blocks [0,8192) handle 3 activation tensors,
// blocks [8192,9216) handle 4 weight tensors.
__global__ __launch_bounds__(256) void cvt_all(const float4* __restrict__ q,
                                               const float4* __restrict__ k,
                                               const float4* __restrict__ v,
                                               const float4* __restrict__ wq,
                                               const float4* __restrict__ wk,
                                               const float4* __restrict__ wv,
                                               const float4* __restrict__ wo,
                                               short4v* __restrict__ dq,
                                               short4v* __restrict__ dk,
                                               short4v* __restrict__ dv,
                                               short4v* __restrict__ dwq,
                                               short4v* __restrict__ dwk,
                                               short4v* __restrict__ dwv,
                                               short4v* __restrict__ dwo) {
    int bid = blockIdx.x;
    float4 x;
    short4v s;
    if (bid < 8192) {
        int i = bid * 256 + threadIdx.x;  // n4 = 2097152
        x = q[i]; s.x = f2bs(x.x); s.y = f2bs(x.y); s.z = f2bs(x.z); s.w = f2bs(x.w); dq[i] = s;
        x = k[i]; s.x = f2bs(x.x); s.y = f2bs(x.y); s.z = f2bs(x.z); s.w = f2bs(x.w); dk[i] = s;
        x = v[i]; s.x = f2bs(x.x); s.y = f2bs(x.y); s.z = f2bs(x.z); s.w = f2bs(x.w); dv[i] = s;
    } else {
        int i = (bid - 8192) * 256 + threadIdx.x;  // n4 = 262144
        x = wq[i]; s.x = f2bs(x.x); s.y = f2bs(x.y); s.z = f2bs(x.z); s.w = f2bs(x.w); dwq[i] = s;
        x = wk[i]; s.x = f2bs(x.x); s.y = f2bs(x.y); s.z = f2bs(x.z); s.w = f2bs(x.w); dwk[i] = s;
        x = wv[i]; s.x = f2bs(x.x); s.y = f2bs(x.y); s.z = f2bs(x.z); s.w = f2bs(x.w); dwv[i] = s;
        x = wo[i]; s.x = f2bs(x.x); s.y = f2bs(x.y); s.z = f2bs(x.z); s.w = f2bs(x.w); dwo[i] = s;
    }
}

// Shared GEMM body: C[m][n] = sum_k A[m][k]*B[n][k], tile 128x128, K=1024.
// 2-phase double-buffered pipeline, BK=32: stage(kt+1) issued BEFORE compute(kt),
// one barrier per tile, so global->LDS latency hides under the MFMA phase.
// Row-pair packing: 16-B chunk i holds row r=2L+(cc&1), k-chunk c=cc>>1 where
// L=i>>3, cc=(i&7)^(L&7) -> bank-conflict-free on both staging and frag reads.
template <typename EpiT>
DEVI void gemm_body(const short* A, const short* Bw, short* smem, int m0, int n0, EpiT epi) {
    const int t = threadIdx.x;
    const int lane = t & 63, w = t >> 6;
    const int col = lane & 15, quad = lane >> 4;
    const int wm = (w & 1) * 64, wn = (w >> 1) * 64;

    // per-lane global staging sources (advance +32 shorts per kt)
    const short* pA0;
    const short* pA1;
    const short* pB0;
    const short* pB1;
    {
        int i0 = w * 64 + lane, i1 = (4 + w) * 64 + lane;
        int L0 = i0 >> 3, cc0 = (i0 & 7) ^ (L0 & 7);
        int r0 = 2 * L0 + (cc0 & 1), c0 = cc0 >> 1;
        int L1 = i1 >> 3, cc1 = (i1 & 7) ^ (L1 & 7);
        int r1 = 2 * L1 + (cc1 & 1), c1 = cc1 >> 1;
        pA0 = A + (size_t)(m0 + r0) * 1024 + c0 * 8;
        pA1 = A + (size_t)(m0 + r1) * 1024 + c1 * 8;
        pB0 = Bw + (size_t)(n0 + r0) * 1024 + c0 * 8;
        pB1 = Bw + (size_t)(n0 + r1) * 1024 + c1 * 8;
    }
    // frag read bases (shorts): row = wm+i*16+col, chunk = quad
    const int posa = (2 * quad + (col & 1)) ^ (col >> 1);
    const int base_a = wm * 32 + (col >> 1) * 64 + posa * 8;
    const int base_b = wn * 32 + (col >> 1) * 64 + posa * 8;

    f32x4 acc[4][4];
#pragma unroll
    for (int i = 0; i < 4; ++i)
#pragma unroll
        for (int j = 0; j < 4; ++j) acc[i][j] = (f32x4){0.f, 0.f, 0.f, 0.f};

    // prologue: stage tile 0 into buffer 0
    glds16(pA0, smem + w * 512);
    glds16(pA1, smem + (4 + w) * 512);
    glds16(pB0, smem + 4096 + w * 512);
    glds16(pB1, smem + 4096 + (4 + w) * 512);
    pA0 += 32; pA1 += 32; pB0 += 32; pB1 += 32;
    __syncthreads();

#pragma unroll 2
    for (int kt = 0; kt < 32; ++kt) {
        const int cur = kt & 1;
        const short* Cb = smem + cur * 8192;
        if (kt < 31) {  // issue next-tile stage BEFORE compute
            short* Nb = smem + (cur ^ 1) * 8192;
            glds16(pA0, Nb + w * 512);
            glds16(pA1, Nb + (4 + w) * 512);
            glds16(pB0, Nb + 4096 + w * 512);
            glds16(pB1, Nb + 4096 + (4 + w) * 512);
            pA0 += 32; pA1 += 32; pB0 += 32; pB1 += 32;
        }
        short8 a[4], b[4];
#pragma unroll
        for (int i = 0; i < 4; ++i) a[i] = *(const short8*)(Cb + base_a + i * 512);
#pragma unroll
        for (int i = 0; i < 4; ++i) b[i] = *(const short8*)(Cb + 4096 + base_b + i * 512);
        __builtin_amdgcn_s_setprio(1);
#pragma unroll
        for (int mi = 0; mi < 4; ++mi)
#pragma unroll
            for (int ni = 0; ni < 4; ++ni)
                acc[mi][ni] = mfma16(a[mi], b[ni], acc[mi][ni]);
        __builtin_amdgcn_s_setprio(0);
        __syncthreads();
    }
    epi(acc, wm, wn, col, quad);
}

// Fused Q/K/V projection. XCD-aware bijective swizzle: 1536 blocks = 8 XCDs x 192;
// each XCD gets 24 contiguous m-tiles of one projection -> A-tile sharers co-locate
// on one L2, W panel L2-resident. (vpt does not alias xk, so the z-interleaved
// dispatch order this swizzle creates is race-free.)
__global__ __launch_bounds__(256) void qkv_gemm(const short* __restrict__ xq,
                                                const short* __restrict__ xk,
                                                const short* __restrict__ xv,
                                                const short* __restrict__ wq,
                                                const short* __restrict__ wk,
                                                const short* __restrict__ wv,
                                                short* __restrict__ qp,
                                                short* __restrict__ kp,
                                                short* __restrict__ vpt, float qscale) {
    __shared__ __align__(16) short smem[17408];  // staging 16384 | T 128x136
    const int lin = blockIdx.x + (blockIdx.y << 3) + (blockIdx.z << 9);
    const int wgid = (lin & 7) * 192 + (lin >> 3);
    const int n0 = (wgid & 7) * 128;
    const int m0 = ((wgid >> 3) & 63) * 128;
    const int z = wgid >> 9;
    const short* A = (z == 0) ? xq : (z == 1) ? xk : xv;
    const short* W = (z == 0) ? wq : (z == 1) ? wk : wv;

    if (z < 2) {
        short* outs = (z == 0) ? qp : kp;
        const float scale = (z == 0) ? qscale : 1.0f;
        gemm_body(A, W, smem, m0, n0, [&](f32x4 (&acc)[4][4], int wm, int wn, int col, int quad) {
            short* T = smem;  // [128 m][136 n-padded]
#pragma unroll
            for (int mi = 0; mi < 4; ++mi)
#pragma unroll
                for (int ni = 0; ni < 4; ++ni)
#pragma unroll
                    for (int r = 0; r < 4; ++r)
                        T[(wm + mi * 16 + quad * 4 + r) * 136 + wn + ni * 16 + col] =
                            f2bs(acc[mi][ni][r] * scale);
            __syncthreads();
            int t = threadIdx.x;
            int ml = t >> 1, nh = (t & 1) * 64;
            int m = m0 + ml;                    // b*2048+s
            int b = m >> 11, s = m & 2047;
#pragma unroll
            for (int j = 0; j < 8; ++j) {
                int n = n0 + nh + j * 8;        // h*64+dk
                short8 vv = *(const short8*)(T + ml * 136 + nh + j * 8);
                size_t off = ((size_t)(b * 16 + (n >> 6)) * 2048 + s) * 64 + (n & 63);
                *(short8*)(outs + off) = vv;
            }
        });
    } else {
        gemm_body(A, W, smem, m0, n0, [&](f32x4 (&acc)[4][4], int wm, int wn, int col, int quad) {
            short* T = smem;  // [128 n][132 m]
#pragma unroll
            for (int mi = 0; mi < 4; ++mi)
#pragma unroll
                for (int ni = 0; ni < 4; ++ni) {
                    int n_l = wn + ni * 16 + col;
                    int m_l = wm + mi * 16 + quad * 4;
                    short4v sv;
                    sv.x = f2bs(acc[mi][ni][0]); sv.y = f2bs(acc[mi][ni][1]);
                    sv.z = f2bs(acc[mi][ni][2]); sv.w = f2bs(acc[mi][ni][3]);
                    *(short4v*)(T + n_l * 132 + m_l) = sv;
                }
            __syncthreads();
            int t = threadIdx.x;
            int nrow = t >> 1, mh = (t & 1) * 64;
            int b = m0 >> 11, s0 = m0 & 2047;
            size_t base = ((size_t)(b * 1024 + n0 + nrow)) * 2048 + s0 + mh;
#pragma unroll
            for (int j = 0; j < 16; ++j) {
                unsigned long long vv = *(const unsigned long long*)(T + nrow * 132 + mh + j * 4);
                *(unsigned long long*)(vpt + base + j * 4) = vv;
            }
        });
    }
}

__global__ __launch_bounds__(256) void out_gemm(const short* __restrict__ ao,
                                                const short* __restrict__ wo,
                                                float* __restrict__ outf) {
    __shared__ __align__(16) short smem[16896];
    const int lin = blockIdx.x + (blockIdx.y << 3);
    const int wgid = (lin & 7) * 64 + (lin >> 3);
    const int n0 = (wgid & 7) * 128;
    const int m0 = (wgid >> 3) * 128;
    gemm_body(ao, wo, smem, m0, n0, [&](f32x4 (&acc)[4][4], int wm, int wn, int col, int quad) {
#pragma unroll
        for (int mi = 0; mi < 4; ++mi)
#pragma unroll
            for (int ni = 0; ni < 4; ++ni)
#pragma unroll
                for (int r = 0; r < 4; ++r) {
                    int m = m0 + wm + mi * 16 + quad * 4 + r;
                    int n = n0 + wn + ni * 16 + col;
                    outf[(size_t)m * 1024 + n] = acc[mi][ni][r];
                }
    });
}

// Flash attention, S^T formulation, in-register P redistribution (permlane),
// softmax denominator via ones-MFMA, and 2-phase double-buffered K/V pipeline.
// LDS = 32768 B -> 4 blocks/CU. Best-measured config (round 4: 86.9 us, 0 conflicts).
__global__ __launch_bounds__(256, 4) void flash_attn(const short* __restrict__ qp,
                                                     const short* __restrict__ kp,
                                                     const short* __restrict__ vpt,
                                                     short* __restrict__ ao) {
    __shared__ __align__(16) short smem[16384];  // Ks2: [2][4096] | Vs2: [2][4096]
    short* Ks2 = smem;
    short* Vs2 = smem + 8192;

    const int t = threadIdx.x, lane = t & 63, w = t >> 6;
    const int col = lane & 15, quad = lane >> 4;
    const int bh = blockIdx.x, q0 = blockIdx.y * 128;
    const short* qb = qp + (size_t)bh * 2048 * 64;
    const short* kb = kp + (size_t)bh * 2048 * 64;
    const short* vb = vpt + (size_t)bh * 64 * 2048;

    // ---- stage Q tile 128x64 (swizzled) into smem[0..8192) ----
#pragma unroll
    for (int j = 0; j < 4; ++j) {
        int cbase = (j * 4 + w) * 64;
        int c = cbase + lane;
        int row = c >> 3, kc = (c & 7) ^ (row & 7);
        glds16(qb + (size_t)(q0 + row) * 64 + kc * 8, smem + cbase * 8);
    }
    __syncthreads();
    short8 bQ[2][2];
#pragma unroll
    for (int qi = 0; qi < 2; ++qi)
#pragma unroll
        for (int ks = 0; ks < 2; ++ks) {
            int row = w * 32 + qi * 16 + col;
            int kc = (ks * 4 + quad) ^ (col & 7);
            bQ[qi][ks] = *(const short8*)(smem + (row * 8 + kc) * 8);
        }
    __syncthreads();

    // hoisted per-lane LDS read bases (shorts)
    const int base2_0 = col * 64 + ((quad ^ (col & 7)) * 8);
    const int base2_1 = col * 64 + (((4 + quad) ^ (col & 7)) * 8);

    // hoisted per-lane global staging pointers (advance per kt)
    const short* kg0;
    const short* kg1;
    const short* vg0;
    const short* vg1;
    {
        int c0 = w * 64 + lane, c1 = (4 + w) * 64 + lane;
        int r0 = c0 >> 3, p0 = c0 & 7, r1 = c1 >> 3, p1 = c1 & 7;
        kg0 = kb + r0 * 64 + ((p0 ^ (r0 & 7)) * 8);
        kg1 = kb + r1 * 64 + ((p1 ^ (r1 & 7)) * 8);
        vg0 = vb + (size_t)r0 * 2048 + ((p0 ^ (r0 & 7)) * 8);
        vg1 = vb + (size_t)r1 * 2048 + ((p1 ^ (r1 & 7)) * 8);
    }

    f32x4 acc_o[2][4], acc_l[2];
#pragma unroll
    for (int qi = 0; qi < 2; ++qi) {
        acc_l[qi] = (f32x4){0.f, 0.f, 0.f, 0.f};
#pragma unroll
        for (int ni = 0; ni < 4; ++ni) acc_o[qi][ni] = (f32x4){0.f, 0.f, 0.f, 0.f};
    }
    const short ONE = 0x3F80;  // bf16 1.0
    const short8 vones = {ONE, ONE, ONE, ONE, ONE, ONE, ONE, ONE};

    // prefetch tile 0 into buffer 0
    glds16(kg0, Ks2 + w * 512);
    glds16(kg1, Ks2 + (4 + w) * 512);
    glds16(vg0, Vs2 + w * 512);
    glds16(vg1, Vs2 + (4 + w) * 512);
    kg0 += 4096; kg1 += 4096; vg0 += 64; vg1 += 64;
    __syncthreads();

#pragma unroll 2
    for (int kt = 0; kt < 32; ++kt) {
        const int cur = kt & 1;
        if (kt < 31) {  // issue next-tile stage BEFORE compute (latency hides under MFMA)
            const int nxt = cur ^ 1;
            glds16(kg0, Ks2 + nxt * 4096 + w * 512);
            glds16(kg1, Ks2 + nxt * 4096 + (4 + w) * 512);
            glds16(vg0, Vs2 + nxt * 4096 + w * 512);
            glds16(vg1, Vs2 + nxt * 4096 + (4 + w) * 512);
            kg0 += 4096; kg1 += 4096; vg0 += 64; vg1 += 64;
        }
        const short* Ks = Ks2 + cur * 4096;
        const short* Vs = Vs2 + cur * 4096;

#pragma unroll
        for (int g = 0; g < 2; ++g) {  // 32-key groups
            unsigned pdw[2][4];
#pragma unroll
            for (int h = 0; h < 2; ++h) {
                const int kei = g * 2 + h;
                f32x4 st0 = (f32x4){0.f, 0.f, 0.f, 0.f};
                f32x4 st1 = (f32x4){0.f, 0.f, 0.f, 0.f};
                __builtin_amdgcn_s_setprio(1);
                {
                    short8 aK0 = *(const short8*)(Ks + base2_0 + kei * 1024);
                    st0 = mfma16(aK0, bQ[0][0], st0);
                    st1 = mfma16(aK0, bQ[1][0], st1);
                    short8 aK1 = *(const short8*)(Ks + base2_1 + kei * 1024);
                    st0 = mfma16(aK1, bQ[0][1], st0);
                    st1 = mfma16(aK1, bQ[1][1], st1);
                }
                __builtin_amdgcn_s_setprio(0);
                {
                    float p0 = __builtin_amdgcn_exp2f(st0[0]);
                    float p1 = __builtin_amdgcn_exp2f(st0[1]);
                    float p2 = __builtin_amdgcn_exp2f(st0[2]);
                    float p3 = __builtin_amdgcn_exp2f(st0[3]);
                    pdw[0][h * 2] = pack2(p0, p1);
                    pdw[0][h * 2 + 1] = pack2(p2, p3);
                }
                {
                    float p0 = __builtin_amdgcn_exp2f(st1[0]);
                    float p1 = __builtin_amdgcn_exp2f(st1[1]);
                    float p2 = __builtin_amdgcn_exp2f(st1[2]);
                    float p3 = __builtin_amdgcn_exp2f(st1[3]);
                    pdw[1][h * 2] = pack2(p0, p1);
                    pdw[1][h * 2 + 1] = pack2(p2, p3);
                }
            }
            // in-register redistribution: quad q ends up with keys g*32 + q*8 .. q*8+7
            xchg(pdw[0][0], pdw[0][2]);
            xchg(pdw[0][1], pdw[0][3]);
            xchg(pdw[1][0], pdw[1][2]);
            xchg(pdw[1][1], pdw[1][3]);
            u32x4 pv0 = {pdw[0][0], pdw[0][1], pdw[0][2], pdw[0][3]};
            u32x4 pv1 = {pdw[1][0], pdw[1][1], pdw[1][2], pdw[1][3]};
            short8 pa0 = __builtin_bit_cast(short8, pv0);
            short8 pa1 = __builtin_bit_cast(short8, pv1);

            const int vb2 = (g == 0) ? base2_0 : base2_1;
            __builtin_amdgcn_s_setprio(1);
#pragma unroll
            for (int ni = 0; ni < 4; ++ni) {
                short8 bv = *(const short8*)(Vs + vb2 + ni * 1024);
                acc_o[0][ni] = mfma16(pa0, bv, acc_o[0][ni]);
                acc_o[1][ni] = mfma16(pa1, bv, acc_o[1][ni]);
            }
            // softmax denominator via ones-MFMA: lands in the epilogue's C layout
            acc_l[0] = mfma16(pa0, vones, acc_l[0]);
            acc_l[1] = mfma16(pa1, vones, acc_l[1]);
            __builtin_amdgcn_s_setprio(0);
        }
        __syncthreads();
    }

    // epilogue: l is already per-lane in C layout (row = quad*4+r), no shuffles
    const int b = bh >> 4, hd = bh & 15;
#pragma unroll
    for (int qi = 0; qi < 2; ++qi)
#pragma unroll
        for (int r = 0; r < 4; ++r) {
            float inv = 1.0f / acc_l[qi][r];
            int q = q0 + w * 32 + qi * 16 + quad * 4 + r;
#pragma unroll
            for (int ni = 0; ni < 4; ++ni)
                ao[((size_t)(b * 2048 + q)) * 1024 + hd * 64 + ni * 16 + col] =
                    f2bs(acc_o[qi][ni][r] * inv);
        }
}

extern "C" void kernel_launch(void* const* d_in, const int* in_sizes, int n_in,
                              void* d_out, int out_size, void* d_ws, size_t ws_size,
                              hipStream_t stream) {
    const float* q  = (const float*)d_in[0];
    const float* k  = (const float*)d_in[1];
    const float* v  = (const float*)d_in[2];
    const float* Wq = (const float*)d_in[3];
    const float* Wk = (const float*)d_in[4];
    const float* Wv = (const float*)d_in[5];
    const float* Wo = (const float*)d_in[6];
    float* out = (float*)d_out;

    short* ws = (short*)d_ws;
    const size_t SZ = (size_t)64 * 2048 * 64;  // 8,388,608
    const size_t WZ = (size_t)1024 * 1024;
    short* xq  = ws;               // later: ao (safe: flash starts after qkv completes)
    short* xk  = ws + SZ;
    short* xv  = ws + 2 * SZ;
    short* qp  = ws + 3 * SZ;
    short* kp  = ws + 4 * SZ;
    short* wqb = ws + 5 * SZ;
    short* wkb = wqb + WZ;
    short* wvb = wqb + 2 * WZ;
    short* wob = wqb + 3 * WZ;
    short* ao  = xq;
    // vpt lives in the OUTPUT buffer (16.8 MB needed, 33.5 MB available):
    // qkv writes it, flash reads it, out_gemm overwrites the region with final floats.
    short* vpt = (short*)d_out;

    const float QSCALE = 0.125f * 1.44269504088896f;  // 1/sqrt(64) * log2(e)

    cvt_all<<<dim3(9216), dim3(256), 0, stream>>>(
        (const float4*)q, (const float4*)k, (const float4*)v, (const float4*)Wq,
        (const float4*)Wk, (const float4*)Wv, (const float4*)Wo, (short4v*)xq, (short4v*)xk,
        (short4v*)xv, (short4v*)wqb, (short4v*)wkb, (short4v*)wvb, (short4v*)wob);
    dim3 blk(256);
    qkv_gemm<<<dim3(8, 64, 3), blk, 0, stream>>>(xq, xk, xv, wqb, wkb, wvb, qp, kp, vpt, QSCALE);
    flash_attn<<<dim3(64, 16), blk, 0, stream>>>(qp, kp, vpt, ao);
    out_gemm<<<dim3(8, 64), blk, 0, stream>>>(ao, wob, out);
}